// Round 7
// baseline (93.182 us; speedup 1.0000x reference)
//
#include <hip/hip_runtime.h>
#include <math.h>

#define B_ 4
#define T_ 512
#define D_ 128
#define H_ 64
#define DEMO_ 12
#define LOG2E 1.4426950408889634f
#define SC2   (2.0f * LOG2E)          // fold tanh's 2x and the exp2 conversion

typedef float float4v __attribute__((ext_vector_type(4)));
typedef float float2v __attribute__((ext_vector_type(2)));

// ---- kernel 1: Q' = (input@Wt)*SC2 [B*T,H]; K2T' = ((input@Wx)+demo@Wd+bh)*SC2 [B,H,T]
__global__ __launch_bounds__(256) void prep_kernel(
    const float* __restrict__ input, const float* __restrict__ demo,
    const float* __restrict__ Wt, const float* __restrict__ Wx,
    const float* __restrict__ Wd, const float* __restrict__ bh,
    const float* __restrict__ Wa, const float* __restrict__ ba,
    float* __restrict__ Q, float* __restrict__ K2T, float* __restrict__ Cs)
{
    __shared__ float in_sh[8 * D_];
    int tid  = threadIdx.x;
    int row0 = blockIdx.x * 8;
    int b    = row0 >> 9;               // T_ == 512

    #pragma unroll
    for (int k = 0; k < 4; ++k)
        in_sh[tid + 256 * k] = input[row0 * D_ + tid + 256 * k];
    __syncthreads();

    int h  = tid & 63;
    int rr = tid >> 6;

    float dB = bh[h];
    #pragma unroll
    for (int kk = 0; kk < DEMO_; ++kk)
        dB = fmaf(demo[b * DEMO_ + kk], Wd[kk * H_ + h], dB);

    float q0 = 0.f, q1 = 0.f, x0 = 0.f, x1 = 0.f;
    #pragma unroll 8
    for (int k = 0; k < D_; ++k) {
        float wt = Wt[k * H_ + h];
        float wx = Wx[k * H_ + h];
        float a0 = in_sh[rr * D_ + k];
        float a1 = in_sh[(rr + 4) * D_ + k];
        q0 = fmaf(a0, wt, q0);
        q1 = fmaf(a1, wt, q1);
        x0 = fmaf(a0, wx, x0);
        x1 = fmaf(a1, wx, x1);
    }

    int ra = row0 + rr, rb = row0 + rr + 4;
    Q[ra * H_ + h] = q0 * SC2;
    Q[rb * H_ + h] = q1 * SC2;
    int ta = ra & (T_ - 1), tb = rb & (T_ - 1);
    K2T[(b * H_ + h) * T_ + ta] = (x0 + dB) * SC2;
    K2T[(b * H_ + h) * T_ + tb] = (x1 + dB) * SC2;

    if (blockIdx.x == 0 && tid < 64) {
        float w = Wa[tid];
        #pragma unroll
        for (int off = 32; off; off >>= 1) w += __shfl_down(w, off, 64);
        if (tid == 0) Cs[0] = (ba[0] + w) * LOG2E;
    }
}

// ---- kernel 2: causal scores + softmax + v ----------------------------------
// grid (128, B); 1024 threads = 16 waves; 2 blocks/CU -> 32 waves/CU (R6 had 16).
// Block y owns rows A={2y,2y+1}, B={510-2y,511-2y}: 1026 row-cols of causal
// work in EVERY block. Half u = tid>>9 computes its pair's scores for j=tid&511
// (2 rows/thread: half the chain length of R6, twice the waves to hide latency).
__global__ __launch_bounds__(1024, 8) void attn_kernel(
    const float* __restrict__ input,
    const float* __restrict__ Qs, const float* __restrict__ K2T,
    const float* __restrict__ Wa, const float* __restrict__ Cs,
    float* __restrict__ out_v, float* __restrict__ out_e)
{
    __shared__ float   qsh[H_ * 4];        // [h][r]  r: 0,1=A rows; 2,3=B rows
    __shared__ float   p_sh[T_ * 4];       // [j][r]  unnormalized, masked
    __shared__ float2v red_m[16];          // [wave] 2 rows of that wave's half
    __shared__ float2v red_s[16];
    __shared__ float   partial[32][4 * D_]; // [s][r*128+d]  64 KB

    int tid  = threadIdx.x;
    int y    = blockIdx.x;                 // [0,128)
    int b    = blockIdx.y;
    int lane = tid & 63, wv = tid >> 6;
    int j    = tid & (T_ - 1);
    int u    = tid >> 9;                   // 0 = A pair, 1 = B pair
    int iA0  = 2 * y,       iA1 = iA0 + 1;
    int iB0  = 510 - 2 * y, iB1 = iB0 + 1;
    int i0u  = u ? iB0 : iA0;
    int i1u  = i0u + 1;

    if (tid < 256) {                       // qsh[h*4+r] = Q'[i_r, h]
        int h  = tid >> 2, r = tid & 3;
        int ir = (r < 2) ? (iA0 + r) : (iB0 + r - 2);
        qsh[tid] = Qs[(size_t)(b * T_ + ir) * H_ + h];
    }
    __syncthreads();                       // B0

    const float* k2p = K2T + (size_t)b * H_ * T_ + j;
    float CL = Cs[0];

    float a0 = 0.f, a1 = 0.f;
    if ((j & ~63) <= i1u) {                // wave-uniform activity gate
        #pragma unroll 2
        for (int h0 = 0; h0 < H_; h0 += 8) {
            float kv[8];
            #pragma unroll
            for (int uu = 0; uu < 8; ++uu) kv[uu] = k2p[(size_t)(h0 + uu) * T_];
            #pragma unroll
            for (int uu = 0; uu < 8; ++uu) {
                float wa   = Wa[h0 + uu];                       // s_load
                float2v q2 = *(const float2v*)&qsh[(h0 + uu) * 4 + 2 * u];
                float e0 = __builtin_amdgcn_exp2f(q2[0] + kv[uu]);
                float e1 = __builtin_amdgcn_exp2f(q2[1] + kv[uu]);
                a0 = fmaf(wa, __builtin_amdgcn_rcpf(1.0f + e0), a0);
                a1 = fmaf(wa, __builtin_amdgcn_rcpf(1.0f + e1), a1);
            }
        }
    }

    // causal rowmax == reference's global rowmax after normalization (the
    // pre-mask max cancels in p/(s+1e-7); diagonal term keeps s >= 1).
    float eg0 = (j <= i0u) ? fmaf(-SC2, a0, CL) : -INFINITY;
    float eg1 = (j <= i1u) ? fmaf(-SC2, a1, CL) : -INFINITY;

    float M0 = eg0, M1 = eg1;
    #pragma unroll
    for (int off = 32; off; off >>= 1) {
        M0 = fmaxf(M0, __shfl_down(M0, off, 64));
        M1 = fmaxf(M1, __shfl_down(M1, off, 64));
    }
    if (lane == 0) red_m[wv] = (float2v){M0, M1};
    __syncthreads();                       // B1
    {
        float2v m = red_m[u * 8];
        #pragma unroll
        for (int w = 1; w < 8; ++w) {
            float2v mw = red_m[u * 8 + w];
            m[0] = fmaxf(m[0], mw[0]);
            m[1] = fmaxf(m[1], mw[1]);
        }
        M0 = m[0]; M1 = m[1];
    }

    float p0 = (j <= i0u) ? __builtin_amdgcn_exp2f(eg0 - M0) : 0.0f;
    float p1 = (j <= i1u) ? __builtin_amdgcn_exp2f(eg1 - M1) : 0.0f;
    *(float2v*)&p_sh[j * 4 + 2 * u] = (float2v){p0, p1};

    float S0 = p0, S1 = p1;
    #pragma unroll
    for (int off = 32; off; off >>= 1) {
        S0 += __shfl_down(S0, off, 64);
        S1 += __shfl_down(S1, off, 64);
    }
    if (lane == 0) red_s[wv] = (float2v){S0, S1};
    __syncthreads();                       // B2 (covers red_s and p_sh)

    float inv[4];
    {
        float2v sA = red_s[0], sB = red_s[8];
        #pragma unroll
        for (int w = 1; w < 8; ++w) {
            float2v aw = red_s[w], bw = red_s[8 + w];
            sA[0] += aw[0]; sA[1] += aw[1];
            sB[0] += bw[0]; sB[1] += bw[1];
        }
        inv[0] = __builtin_amdgcn_rcpf(sA[0] + 1e-7f);
        inv[1] = __builtin_amdgcn_rcpf(sA[1] + 1e-7f);
        inv[2] = __builtin_amdgcn_rcpf(sB[0] + 1e-7f);
        inv[3] = __builtin_amdgcn_rcpf(sB[1] + 1e-7f);
    }

    // e-writes now: stores overlap the v-phase compute below
    out_e[((size_t)(b * T_ + i0u)) * T_ + j] = p0 * inv[2 * u];
    out_e[((size_t)(b * T_ + i1u)) * T_ + j] = p1 * inv[2 * u + 1];

    // v-phase: thread = (s-chunk of 16 j, d4 of 4 d). dwordx4 input loads,
    // b128 broadcast p reads, 16 fma per j. Unnormalized partials.
    {
        int s = tid >> 5, d4 = tid & 31;   // s: 0..31
        float4v va0 = {0,0,0,0}, va1 = {0,0,0,0}, va2 = {0,0,0,0}, va3 = {0,0,0,0};
        if ((s << 4) <= iB1) {             // chunk has at least one unmasked j
            const float* inp = input + ((size_t)(b * T_) + (s << 4)) * D_ + (d4 << 2);
            const float* pp  = p_sh + (s << 4) * 4;
            #pragma unroll 4
            for (int jj = 0; jj < 16; ++jj) {
                float4v x  = *(const float4v*)(inp + (size_t)jj * D_);
                float4v p4 = *(const float4v*)(pp + jj * 4);
                va0 += x * p4[0];
                va1 += x * p4[1];
                va2 += x * p4[2];
                va3 += x * p4[3];
            }
        }
        *(float4v*)&partial[s][0 * D_ + (d4 << 2)] = va0;
        *(float4v*)&partial[s][1 * D_ + (d4 << 2)] = va1;
        *(float4v*)&partial[s][2 * D_ + (d4 << 2)] = va2;
        *(float4v*)&partial[s][3 * D_ + (d4 << 2)] = va3;
    }
    __syncthreads();                       // B3

    if (tid < 512) {
        int r = tid >> 7, d = tid & 127;
        float v = 0.f;
        #pragma unroll
        for (int ss = 0; ss < 32; ++ss) v += partial[ss][r * D_ + d];
        int ir = (r < 2) ? (iA0 + r) : (iB0 + r - 2);
        out_v[(size_t)(b * T_ + ir) * D_ + d] = v * inv[r];
    }
}

extern "C" void kernel_launch(void* const* d_in, const int* in_sizes, int n_in,
                              void* d_out, int out_size, void* d_ws, size_t ws_size,
                              hipStream_t stream)
{
    const float* input = (const float*)d_in[0];
    const float* demo  = (const float*)d_in[1];
    const float* Wt    = (const float*)d_in[2];
    const float* Wx    = (const float*)d_in[3];
    const float* Wd    = (const float*)d_in[4];
    const float* bh    = (const float*)d_in[5];
    const float* Wa    = (const float*)d_in[6];
    const float* ba    = (const float*)d_in[7];

    float* out_v = (float*)d_out;                     // [B,T,D]
    float* out_e = out_v + (size_t)B_ * T_ * D_;      // [B,T,T]

    float* Q   = (float*)d_ws;                        // [B*T, H]  (pre-scaled)
    float* K2T = Q + (size_t)B_ * T_ * H_;            // [B, H, T] (pre-scaled)
    float* Cs  = K2T + (size_t)B_ * H_ * T_;          // [1]

    prep_kernel<<<dim3(B_ * T_ / 8), 256, 0, stream>>>(input, demo, Wt, Wx, Wd, bh,
                                                       Wa, ba, Q, K2T, Cs);
    attn_kernel<<<dim3(128, B_), 1024, 0, stream>>>(input, Q, K2T, Wa, Cs, out_v, out_e);
}

// Round 8
// 92.977 us; speedup vs baseline: 1.0022x; 1.0022x over previous
//
#include <hip/hip_runtime.h>
#include <math.h>

#define B_ 4
#define T_ 512
#define D_ 128
#define H_ 64
#define DEMO_ 12
#define LOG2E 1.4426950408889634f
#define SC2   (2.0f * LOG2E)          // fold tanh's 2x and the exp2 conversion

typedef float    float4v __attribute__((ext_vector_type(4)));
typedef float    float2v __attribute__((ext_vector_type(2)));
typedef unsigned uint2v  __attribute__((ext_vector_type(2)));

// ---- kernel 1: Q' = (input@Wt)*SC2 [B*T,H]; K2T' = ((input@Wx)+demo@Wd+bh)*SC2 [B,H,T]
__global__ __launch_bounds__(256) void prep_kernel(
    const float* __restrict__ input, const float* __restrict__ demo,
    const float* __restrict__ Wt, const float* __restrict__ Wx,
    const float* __restrict__ Wd, const float* __restrict__ bh,
    const float* __restrict__ Wa, const float* __restrict__ ba,
    float* __restrict__ Q, float* __restrict__ K2T, float* __restrict__ Cs)
{
    __shared__ float in_sh[8 * D_];
    int tid  = threadIdx.x;
    int row0 = blockIdx.x * 8;
    int b    = row0 >> 9;               // T_ == 512

    #pragma unroll
    for (int k = 0; k < 4; ++k)
        in_sh[tid + 256 * k] = input[row0 * D_ + tid + 256 * k];
    __syncthreads();

    int h  = tid & 63;
    int rr = tid >> 6;

    float dB = bh[h];
    #pragma unroll
    for (int kk = 0; kk < DEMO_; ++kk)
        dB = fmaf(demo[b * DEMO_ + kk], Wd[kk * H_ + h], dB);

    float q0 = 0.f, q1 = 0.f, x0 = 0.f, x1 = 0.f;
    #pragma unroll 8
    for (int k = 0; k < D_; ++k) {
        float wt = Wt[k * H_ + h];
        float wx = Wx[k * H_ + h];
        float a0 = in_sh[rr * D_ + k];
        float a1 = in_sh[(rr + 4) * D_ + k];
        q0 = fmaf(a0, wt, q0);
        q1 = fmaf(a1, wt, q1);
        x0 = fmaf(a0, wx, x0);
        x1 = fmaf(a1, wx, x1);
    }

    int ra = row0 + rr, rb = row0 + rr + 4;
    Q[ra * H_ + h] = q0 * SC2;
    Q[rb * H_ + h] = q1 * SC2;
    int ta = ra & (T_ - 1), tb = rb & (T_ - 1);
    K2T[(b * H_ + h) * T_ + ta] = (x0 + dB) * SC2;
    K2T[(b * H_ + h) * T_ + tb] = (x1 + dB) * SC2;

    if (blockIdx.x == 0 && tid < 64) {
        float w = Wa[tid];
        #pragma unroll
        for (int off = 32; off; off >>= 1) w += __shfl_down(w, off, 64);
        if (tid == 0) Cs[0] = (ba[0] + w) * LOG2E;
    }
}

// ---- kernel 2: causal scores + softmax + v ----------------------------------
// grid (128, B); 1024 threads = 16 waves; 2 blocks/CU -> 32 waves/CU.
// Block y owns rows A={2y,2y+1}, B={510-2y,511-2y}: 1026 row-cols of causal
// work in EVERY block. Half u = tid>>9 computes its pair for j = tid&511.
// Inner loop: 1/(1+2^t) via integer-magic reciprocal + 1 Newton (no v_rcp
// trans op), float2-packed VALU (v_pk_* dual-issue fp32) -> ~15 cy/element.
__global__ __launch_bounds__(1024, 8) void attn_kernel(
    const float* __restrict__ input,
    const float* __restrict__ Qs, const float* __restrict__ K2T,
    const float* __restrict__ Wa, const float* __restrict__ Cs,
    float* __restrict__ out_v, float* __restrict__ out_e)
{
    __shared__ float   qsh[H_ * 4];        // [h][r]  r: 0,1=A rows; 2,3=B rows
    __shared__ float   p_sh[T_ * 4];       // [j][r]  unnormalized, masked
    __shared__ float2v red_m[16];          // [wave] 2 rows of that wave's half
    __shared__ float2v red_s[16];
    __shared__ float   partial[32][4 * D_]; // [s][r*128+d]  64 KB

    int tid  = threadIdx.x;
    int y    = blockIdx.x;                 // [0,128)
    int b    = blockIdx.y;
    int lane = tid & 63, wv = tid >> 6;
    int j    = tid & (T_ - 1);
    int u    = tid >> 9;                   // 0 = A pair, 1 = B pair
    int iA0  = 2 * y,       iA1 = iA0 + 1;
    int iB0  = 510 - 2 * y, iB1 = iB0 + 1;
    int i0u  = u ? iB0 : iA0;
    int i1u  = i0u + 1;

    if (tid < 256) {                       // qsh[h*4+r] = Q'[i_r, h]
        int h  = tid >> 2, r = tid & 3;
        int ir = (r < 2) ? (iA0 + r) : (iB0 + r - 2);
        qsh[tid] = Qs[(size_t)(b * T_ + ir) * H_ + h];
    }
    __syncthreads();                       // B0

    const float* k2p = K2T + (size_t)b * H_ * T_ + j;
    float CL = Cs[0];

    float2v acc = {0.f, 0.f};
    if ((j & ~63) <= i1u) {                // wave-uniform activity gate
        #pragma unroll 2
        for (int h0 = 0; h0 < H_; h0 += 8) {
            float kv[8];
            #pragma unroll
            for (int uu = 0; uu < 8; ++uu) kv[uu] = k2p[(size_t)(h0 + uu) * T_];
            #pragma unroll
            for (int uu = 0; uu < 8; ++uu) {
                float wa   = Wa[h0 + uu];                       // s_load
                float2v q2 = *(const float2v*)&qsh[(h0 + uu) * 4 + 2 * u];
                float2v x  = q2 + kv[uu];                       // pk_add
                // ex = 2^x  (x pre-scaled by 2*log2e in prep; |x| < ~40)
                float2v ex = {__builtin_amdgcn_exp2f(x[0]),
                              __builtin_amdgcn_exp2f(x[1])};
                float2v d  = ex + 1.0f;                         // pk_add
                uint2v  db;
                __builtin_memcpy(&db, &d, 8);
                uint2v  rb = (uint2v){0x7EF311C3u, 0x7EF311C3u} - db;
                float2v r0;
                __builtin_memcpy(&r0, &rb, 8);
                float2v r  = r0 * (2.0f - d * r0);              // 1 Newton
                acc += wa * r;                                  // pk_fma
            }
        }
    }

    // causal rowmax == reference's global rowmax after normalization (the
    // pre-mask max cancels in p/(s+1e-7); diagonal term keeps s >= 1).
    float eg0 = (j <= i0u) ? fmaf(-SC2, acc[0], CL) : -INFINITY;
    float eg1 = (j <= i1u) ? fmaf(-SC2, acc[1], CL) : -INFINITY;

    float M0 = eg0, M1 = eg1;
    #pragma unroll
    for (int off = 32; off; off >>= 1) {
        M0 = fmaxf(M0, __shfl_down(M0, off, 64));
        M1 = fmaxf(M1, __shfl_down(M1, off, 64));
    }
    if (lane == 0) red_m[wv] = (float2v){M0, M1};
    __syncthreads();                       // B1
    {
        float2v m = red_m[u * 8];
        #pragma unroll
        for (int w = 1; w < 8; ++w) {
            float2v mw = red_m[u * 8 + w];
            m[0] = fmaxf(m[0], mw[0]);
            m[1] = fmaxf(m[1], mw[1]);
        }
        M0 = m[0]; M1 = m[1];
    }

    float p0 = (j <= i0u) ? __builtin_amdgcn_exp2f(eg0 - M0) : 0.0f;
    float p1 = (j <= i1u) ? __builtin_amdgcn_exp2f(eg1 - M1) : 0.0f;
    *(float2v*)&p_sh[j * 4 + 2 * u] = (float2v){p0, p1};

    float S0 = p0, S1 = p1;
    #pragma unroll
    for (int off = 32; off; off >>= 1) {
        S0 += __shfl_down(S0, off, 64);
        S1 += __shfl_down(S1, off, 64);
    }
    if (lane == 0) red_s[wv] = (float2v){S0, S1};
    __syncthreads();                       // B2 (covers red_s and p_sh)

    float inv[4];
    {
        float2v sA = red_s[0], sB = red_s[8];
        #pragma unroll
        for (int w = 1; w < 8; ++w) {
            float2v aw = red_s[w], bw = red_s[8 + w];
            sA[0] += aw[0]; sA[1] += aw[1];
            sB[0] += bw[0]; sB[1] += bw[1];
        }
        inv[0] = __builtin_amdgcn_rcpf(sA[0] + 1e-7f);
        inv[1] = __builtin_amdgcn_rcpf(sA[1] + 1e-7f);
        inv[2] = __builtin_amdgcn_rcpf(sB[0] + 1e-7f);
        inv[3] = __builtin_amdgcn_rcpf(sB[1] + 1e-7f);
    }

    // e-writes now: stores overlap the v-phase compute below
    out_e[((size_t)(b * T_ + i0u)) * T_ + j] = p0 * inv[2 * u];
    out_e[((size_t)(b * T_ + i1u)) * T_ + j] = p1 * inv[2 * u + 1];

    // v-phase: thread = (s-chunk of 16 j, d4 of 4 d). dwordx4 input loads,
    // b128 broadcast p reads. Unnormalized partials.
    {
        int s = tid >> 5, d4 = tid & 31;   // s: 0..31
        float4v va0 = {0,0,0,0}, va1 = {0,0,0,0}, va2 = {0,0,0,0}, va3 = {0,0,0,0};
        if ((s << 4) <= iB1) {             // chunk has at least one unmasked j
            const float* inp = input + ((size_t)(b * T_) + (s << 4)) * D_ + (d4 << 2);
            const float* pp  = p_sh + (s << 4) * 4;
            #pragma unroll 4
            for (int jj = 0; jj < 16; ++jj) {
                float4v x  = *(const float4v*)(inp + (size_t)jj * D_);
                float4v p4 = *(const float4v*)(pp + jj * 4);
                va0 += x * p4[0];
                va1 += x * p4[1];
                va2 += x * p4[2];
                va3 += x * p4[3];
            }
        }
        *(float4v*)&partial[s][0 * D_ + (d4 << 2)] = va0;
        *(float4v*)&partial[s][1 * D_ + (d4 << 2)] = va1;
        *(float4v*)&partial[s][2 * D_ + (d4 << 2)] = va2;
        *(float4v*)&partial[s][3 * D_ + (d4 << 2)] = va3;
    }
    __syncthreads();                       // B3

    if (tid < 512) {
        int r = tid >> 7, d = tid & 127;
        float v = 0.f;
        #pragma unroll
        for (int ss = 0; ss < 32; ++ss) v += partial[ss][r * D_ + d];
        int ir = (r < 2) ? (iA0 + r) : (iB0 + r - 2);
        out_v[(size_t)(b * T_ + ir) * D_ + d] = v * inv[r];
    }
}

extern "C" void kernel_launch(void* const* d_in, const int* in_sizes, int n_in,
                              void* d_out, int out_size, void* d_ws, size_t ws_size,
                              hipStream_t stream)
{
    const float* input = (const float*)d_in[0];
    const float* demo  = (const float*)d_in[1];
    const float* Wt    = (const float*)d_in[2];
    const float* Wx    = (const float*)d_in[3];
    const float* Wd    = (const float*)d_in[4];
    const float* bh    = (const float*)d_in[5];
    const float* Wa    = (const float*)d_in[6];
    const float* ba    = (const float*)d_in[7];

    float* out_v = (float*)d_out;                     // [B,T,D]
    float* out_e = out_v + (size_t)B_ * T_ * D_;      // [B,T,T]

    float* Q   = (float*)d_ws;                        // [B*T, H]  (pre-scaled)
    float* K2T = Q + (size_t)B_ * T_ * H_;            // [B, H, T] (pre-scaled)
    float* Cs  = K2T + (size_t)B_ * H_ * T_;          // [1]

    prep_kernel<<<dim3(B_ * T_ / 8), 256, 0, stream>>>(input, demo, Wt, Wx, Wd, bh,
                                                       Wa, ba, Q, K2T, Cs);
    attn_kernel<<<dim3(128, B_), 1024, 0, stream>>>(input, Q, K2T, Wa, Cs, out_v, out_e);
}